// Round 9
// baseline (92.983 us; speedup 1.0000x reference)
//
#include <hip/hip_runtime.h>
#include <hip/hip_bf16.h>
#include <math.h>

// Problem constants (match reference)
#define BB      8
#define C_CH    128
#define HH      256
#define WW      256
#define N_POS   2048
#define N_NEG   8192
#define N_ROWS  (N_POS + N_NEG)     // 10240
#define EPS_N   1e-6f

// sim tiling: block = 4 waves as 2x2, each wave 64x64 output, K=128 in 4 steps
#define NIB     (N_POS / 128)       // 16
#define NJB     (N_ROWS / 128)      // 80
#define NJSLAB      (N_ROWS / 64)   // 160 j-slabs of 64 cols (per-wave extent)
#define NJSLAB_POS  (N_POS / 64)    // 32

// LDS staging for sim: per K-step of 32, four arrays (A-hi, A-lo, B-hi, B-lo),
// each 128 rows x 64B data with row stride 80B (16B pad) -> conflict-free
// ds_read_b128 / ds_write_b128 (quad index (5*row + g) % 8 is distinct over
// any 8 consecutive lanes; residual aliasing is 2-way = free).
#define RSTRIDE 80
#define ARR_SZ  (128 * RSTRIDE)     // 10240 B
#define LDS_SZ  (4 * ARR_SZ)        // 40 KB

typedef __attribute__((ext_vector_type(8))) short bf16x8;   // 8 bf16 = 4 VGPR
typedef __attribute__((ext_vector_type(4))) float f32x4;    // MFMA C/D

// Workspace layout:
//   hi:      [N_ROWS][128] bf16   @ 0              (2.62 MB)
//   lo:      [N_ROWS][128] bf16   @ 2.62 MB        (2.62 MB)
//   partial: [NJSLAB][N_POS] f32                   (1.31 MB)
//   term:    [N_POS] f32                           (8 KB)

// ---------------------------------------------------------------------------
// Kernel 1: gather + L2-normalize + split to bf16 hi/lo. (r7 form: 1 row/wave,
// measured best.) Lane l owns channels l and l+64.
__global__ __launch_bounds__(256) void gather_norm_kernel(
    const float* __restrict__ seg,
    const int* __restrict__ pb, const int* __restrict__ ph, const int* __restrict__ pw,
    const int* __restrict__ nb, const int* __restrict__ nh, const int* __restrict__ nw,
    __hip_bfloat16* __restrict__ hi, __hip_bfloat16* __restrict__ lo)
{
    const int wave = threadIdx.x >> 6;
    const int lane = threadIdx.x & 63;
    const int row  = blockIdx.x * 4 + wave;
    if (row >= N_ROWS) return;

    int b, h, w;
    if (row < N_POS) { b = pb[row]; h = ph[row]; w = pw[row]; }
    else { const int r = row - N_POS; b = nb[r]; h = nh[r]; w = nw[r]; }

    const size_t cs   = (size_t)HH * WW;
    const size_t base = (size_t)b * C_CH * cs + (size_t)h * WW + (size_t)w;

    const float v0 = seg[base + (size_t)lane * cs];
    const float v1 = seg[base + (size_t)(lane + 64) * cs];

    float ss = v0 * v0 + v1 * v1;
#pragma unroll
    for (int m = 1; m < 64; m <<= 1) ss += __shfl_xor(ss, m, 64);

    const float n  = fmaxf(sqrtf(ss), EPS_N);
    const float u0 = v0 / n;
    const float u1 = v1 / n;

    const __hip_bfloat16 h0 = __float2bfloat16(u0);
    const __hip_bfloat16 h1 = __float2bfloat16(u1);
    const __hip_bfloat16 l0 = __float2bfloat16(u0 - __bfloat162float(h0));
    const __hip_bfloat16 l1 = __float2bfloat16(u1 - __bfloat162float(h1));

    const size_t o = (size_t)row * C_CH + lane;
    hi[o]      = h0;  lo[o]      = l0;
    hi[o + 64] = h1;  lo[o + 64] = l1;
}

// ---------------------------------------------------------------------------
// Kernel 2: C[i][j] = dot(x_i, x_j) via 3-term split-bf16 MFMA with
// LDS-staged operand tiles (m97-lite): per K-step, stage 32 KB
// (A-hi/A-lo/B-hi/B-lo) via reg->ds_write_b128 into the padded layout, then
// ds_read_b128 fragments. 4 waves share the panels (halves L2 traffic vs
// direct loads). Epilogue unchanged (deterministic single store per
// (jslab,row)).
__global__ __launch_bounds__(256, 3) void sim_mfma_kernel(
    const __hip_bfloat16* __restrict__ hi_, const __hip_bfloat16* __restrict__ lo_,
    float* __restrict__ partial)
{
    const ushort* __restrict__ hi = (const ushort*)hi_;
    const ushort* __restrict__ lo = (const ushort*)lo_;

    __shared__ __align__(16) unsigned char lds[LDS_SZ];

    const int bid = blockIdx.x;
    const int ib  = bid / NJB;          // 0..15
    const int jb  = bid % NJB;          // 0..79 (ids sharing jb == mod 8 -> same XCD)
    const int t    = threadIdx.x;
    const int wave = t >> 6;
    const int lane = t & 63;
    const int wy = wave >> 1;           // i-half
    const int wx = wave & 1;            // j-half

    const int i0 = ib * 128;
    const int j0 = jb * 128;

    const int lr = lane & 15;           // row/col within 16x16 tile
    const int lk = lane >> 4;           // k-chunk (8 bf16 = 16B)

    f32x4 acc[4][4];
#pragma unroll
    for (int m = 0; m < 4; ++m)
#pragma unroll
        for (int n = 0; n < 4; ++n) acc[m][n] = (f32x4){0.f, 0.f, 0.f, 0.f};

    for (int ks = 0; ks < 4; ++ks) {
        const int kc = ks * 32;         // element offset of this K-step

        // ---- issue the 8 staging loads (global, before touching LDS) ----
        // arrays: 0=A-hi 1=A-lo 2=B-hi 3=B-lo; granule G = q*256 + t,
        // row = G>>2 (0..127), g = G&3 (16B granule within the row's 64B).
        float4 v[8];
#pragma unroll
        for (int a = 0; a < 4; ++a) {
            const ushort* __restrict__ src = (a & 1) ? lo : hi;
            const int rbase = (a < 2) ? i0 : j0;
#pragma unroll
            for (int q = 0; q < 2; ++q) {
                const int G   = q * 256 + t;
                const int row = G >> 2;
                const int g   = G & 3;
                v[a * 2 + q] = *(const float4*)&src[(size_t)(rbase + row) * C_CH + kc + g * 8];
            }
        }

        // previous iteration's ds_reads must be complete before overwriting
        if (ks) __syncthreads();

#pragma unroll
        for (int a = 0; a < 4; ++a) {
#pragma unroll
            for (int q = 0; q < 2; ++q) {
                const int G   = q * 256 + t;
                const int row = G >> 2;
                const int g   = G & 3;
                *(float4*)&lds[a * ARR_SZ + row * RSTRIDE + g * 16] = v[a * 2 + q];
            }
        }
        __syncthreads();

        // ---- fragment reads + MFMA ----
        bf16x8 ah[4], al[4];
#pragma unroll
        for (int m = 0; m < 4; ++m) {
            const int row = wy * 64 + m * 16 + lr;
            ah[m] = *(const bf16x8*)&lds[0 * ARR_SZ + row * RSTRIDE + lk * 16];
            al[m] = *(const bf16x8*)&lds[1 * ARR_SZ + row * RSTRIDE + lk * 16];
        }
#pragma unroll
        for (int n = 0; n < 4; ++n) {
            const int row = wx * 64 + n * 16 + lr;
            const bf16x8 bh = *(const bf16x8*)&lds[2 * ARR_SZ + row * RSTRIDE + lk * 16];
            const bf16x8 bl = *(const bf16x8*)&lds[3 * ARR_SZ + row * RSTRIDE + lk * 16];
#pragma unroll
            for (int m = 0; m < 4; ++m) {
                acc[m][n] = __builtin_amdgcn_mfma_f32_16x16x32_bf16(ah[m], bh, acc[m][n], 0, 0, 0);
                acc[m][n] = __builtin_amdgcn_mfma_f32_16x16x32_bf16(ah[m], bl, acc[m][n], 0, 0, 0);
                acc[m][n] = __builtin_amdgcn_mfma_f32_16x16x32_bf16(al[m], bh, acc[m][n], 0, 0, 0);
            }
        }
    }

    // Epilogue. C/D layout: value r of lane l = C[iw0+m*16+(l>>4)*4+r][jw0+n*16+(l&15)]
    const int iw0 = i0 + wy * 64;
    const int jslab = (j0 + wx * 64) >> 6;   // 0..159
#pragma unroll
    for (int m = 0; m < 4; ++m) {
        float s0 = 0.f, s1 = 0.f, s2 = 0.f, s3 = 0.f;
#pragma unroll
        for (int n = 0; n < 4; ++n) {
            s0 += __expf(acc[m][n][0]);
            s1 += __expf(acc[m][n][1]);
            s2 += __expf(acc[m][n][2]);
            s3 += __expf(acc[m][n][3]);
        }
        float s[4] = {s0, s1, s2, s3};
#pragma unroll
        for (int r = 0; r < 4; ++r) {
            float vv = s[r];
            vv += __shfl_xor(vv, 1, 64);
            vv += __shfl_xor(vv, 2, 64);
            vv += __shfl_xor(vv, 4, 64);
            vv += __shfl_xor(vv, 8, 64);
            if (lr == 0) {
                const int row = iw0 + m * 16 + lk * 4 + r;
                partial[(size_t)jslab * N_POS + row] = vv;
            }
        }
    }
}

// ---------------------------------------------------------------------------
// Kernel 3a: per-row reduction over the 160 j-slab partials (coalesced).
__global__ __launch_bounds__(256) void rowred_kernel(
    const float* __restrict__ partial, float* __restrict__ term)
{
    const int row = blockIdx.x * 256 + threadIdx.x;
    float P = 0.f, Nv = 0.f;
    for (int s = 0; s < NJSLAB_POS; ++s)      P  += partial[(size_t)s * N_POS + row];
    for (int s = NJSLAB_POS; s < NJSLAB; ++s) Nv += partial[(size_t)s * N_POS + row];
    const float p = P - 2.71828182845904523536f;   // remove self-sim exp(1)
    term[row] = logf(p) - logf(p + Nv);
}

// Kernel 3b: single block => deterministic final mean.
__global__ __launch_bounds__(256) void final_kernel(
    const float* __restrict__ term, float* __restrict__ out)
{
    const int t = threadIdx.x;
    float local = 0.f;
    for (int i = t; i < N_POS; i += 256) local += term[i];

    __shared__ float red[256];
    red[t] = local;
    __syncthreads();
    for (int s = 128; s > 0; s >>= 1) {
        if (t < s) red[t] += red[t + s];
        __syncthreads();
    }
    if (t == 0) out[0] = -red[0] / (float)N_POS;
}

// ---------------------------------------------------------------------------
extern "C" void kernel_launch(void* const* d_in, const int* in_sizes, int n_in,
                              void* d_out, int out_size, void* d_ws, size_t ws_size,
                              hipStream_t stream)
{
    const float* seg = (const float*)d_in[0];
    const int* pb = (const int*)d_in[1];
    const int* ph = (const int*)d_in[2];
    const int* pw = (const int*)d_in[3];
    const int* nb = (const int*)d_in[4];
    const int* nh = (const int*)d_in[5];
    const int* nw = (const int*)d_in[6];
    float* out = (float*)d_out;

    __hip_bfloat16* hi = (__hip_bfloat16*)d_ws;
    __hip_bfloat16* lo = hi + (size_t)N_ROWS * C_CH;
    float* partial = (float*)(lo + (size_t)N_ROWS * C_CH);
    float* term    = partial + (size_t)NJSLAB * N_POS;

    gather_norm_kernel<<<dim3((N_ROWS + 3) / 4), dim3(256), 0, stream>>>(
        seg, pb, ph, pw, nb, nh, nw, hi, lo);

    sim_mfma_kernel<<<dim3(NIB * NJB), dim3(256), 0, stream>>>(hi, lo, partial);

    rowred_kernel<<<dim3(N_POS / 256), dim3(256), 0, stream>>>(partial, term);
    final_kernel<<<dim3(1), dim3(256), 0, stream>>>(term, out);
}